// Round 2
// baseline (5699.608 us; speedup 1.0000x reference)
//
#include <hip/hip_runtime.h>
#include <hip/hip_bf16.h>
#include <math.h>

// Starcoder2 attention R2:
//  - GEMMs: bf16 MFMA (16x16x32), 128x128 tile, BK=32, inline fp32->bf16 cvt.
//  - Attention: fp32, register softmax + shuffle butterfly, conflict-free LDS.
// T=2048, HID=4608, H=36, KV=4, D=128, window=1024.

#define T_SEQ   2048
#define HIDDEN  4608
#define NHEAD   36
#define NKVH    4
#define HEADDIM 128
#define GQA_G   9
#define NQKV    5632
#define KOFF    4608
#define VOFF    5120
#define NEG_BIG -1e30f

typedef short bf16x8 __attribute__((ext_vector_type(8)));
typedef float f32x4  __attribute__((ext_vector_type(4)));

// pack 8 fp32 -> 8 bf16 (RNE via v_cvt_pk_bf16_f32)
__device__ inline bf16x8 pack8(float4 u, float4 v) {
    union { bf16x8 v8; __hip_bfloat162 h[4]; } r;
    r.h[0] = __float22bfloat162_rn(make_float2(u.x, u.y));
    r.h[1] = __float22bfloat162_rn(make_float2(u.z, u.w));
    r.h[2] = __float22bfloat162_rn(make_float2(v.x, v.y));
    r.h[3] = __float22bfloat162_rn(make_float2(v.z, v.w));
    return r.v8;
}

// ---------------------------------------------------------------------------
// C[M,N] = A[M,K](fp32) @ B[N,K](fp32)^T + bias, bf16 MFMA, fp32 accumulate.
// 256 thr = 4 waves (2x2 of 64x64). Per wave: 4x4 grid of 16x16x32 MFMA.
// A/B fragments load identically from row-major [idx][k] LDS tiles (gemm_bt).
// C/D layout (m89-verified): col = lane&15, row = (lane>>4)*4 + reg.
// ---------------------------------------------------------------------------
__global__ __launch_bounds__(256)
void gemm_bf16_kernel(const float* __restrict__ A, const float* __restrict__ B,
                      const float* __restrict__ bias, float* __restrict__ C,
                      int N, int K)
{
    __shared__ short As[128 * 32];   // row-major, row stride 32 bf16 (64 B)
    __shared__ short Bs[128 * 32];

    const int tid  = threadIdx.x;
    const int lane = tid & 63;
    const int wave = tid >> 6;
    const int row0 = blockIdx.y * 128;
    const int col0 = blockIdx.x * 128;
    const int wr   = (wave >> 1) * 64;
    const int wc   = (wave & 1) * 64;

    // staging: thread covers rows sr and sr+64, 8-float chunk sk
    const int sr = tid >> 2;          // 0..63
    const int sk = (tid & 3) * 8;     // element offset in K-tile

    const float* Ap  = A + (size_t)(row0 + sr) * K + sk;
    const float* Ap2 = Ap + (size_t)64 * K;
    const float* Bp  = B + (size_t)(col0 + sr) * K + sk;
    const float* Bp2 = Bp + (size_t)64 * K;

    f32x4 acc[4][4];
    #pragma unroll
    for (int i = 0; i < 4; ++i)
        #pragma unroll
        for (int j = 0; j < 4; ++j)
            #pragma unroll
            for (int r = 0; r < 4; ++r) acc[i][j][r] = 0.0f;

    // preload k0 = 0
    float4 a0 = *(const float4*)(Ap),  a1 = *(const float4*)(Ap + 4);
    float4 c0 = *(const float4*)(Ap2), c1 = *(const float4*)(Ap2 + 4);
    float4 b0 = *(const float4*)(Bp),  b1 = *(const float4*)(Bp + 4);
    float4 d0 = *(const float4*)(Bp2), d1 = *(const float4*)(Bp2 + 4);

    const int fr = lane & 15;          // row/col within 16-tile
    const int fk = (lane >> 4) * 8;    // k offset (elements)

    bf16x8* As_w  = (bf16x8*)&As[sr * 32 + sk];
    bf16x8* As_w2 = (bf16x8*)&As[(64 + sr) * 32 + sk];
    bf16x8* Bs_w  = (bf16x8*)&Bs[sr * 32 + sk];
    bf16x8* Bs_w2 = (bf16x8*)&Bs[(64 + sr) * 32 + sk];

    for (int k0 = 0; k0 < K; k0 += 32) {
        __syncthreads();                      // prev iter's ds_reads done
        *As_w  = pack8(a0, a1);
        *As_w2 = pack8(c0, c1);
        *Bs_w  = pack8(b0, b1);
        *Bs_w2 = pack8(d0, d1);
        __syncthreads();

        // prefetch next K-tile; overlaps the MFMA phase below
        if (k0 + 32 < K) {
            Ap += 32; Ap2 += 32; Bp += 32; Bp2 += 32;
            a0 = *(const float4*)(Ap);  a1 = *(const float4*)(Ap + 4);
            c0 = *(const float4*)(Ap2); c1 = *(const float4*)(Ap2 + 4);
            b0 = *(const float4*)(Bp);  b1 = *(const float4*)(Bp + 4);
            d0 = *(const float4*)(Bp2); d1 = *(const float4*)(Bp2 + 4);
        }

        bf16x8 af[4], bfr[4];
        #pragma unroll
        for (int i = 0; i < 4; ++i)
            af[i] = *(const bf16x8*)&As[(wr + i * 16 + fr) * 32 + fk];
        #pragma unroll
        for (int j = 0; j < 4; ++j)
            bfr[j] = *(const bf16x8*)&Bs[(wc + j * 16 + fr) * 32 + fk];

        #pragma unroll
        for (int i = 0; i < 4; ++i)
            #pragma unroll
            for (int j = 0; j < 4; ++j)
                acc[i][j] = __builtin_amdgcn_mfma_f32_16x16x32_bf16(
                    af[i], bfr[j], acc[i][j], 0, 0, 0);
    }

    const int quad = lane >> 4;
    #pragma unroll
    for (int j = 0; j < 4; ++j) {
        const int col = col0 + wc + j * 16 + fr;
        const float bv = bias[col];
        #pragma unroll
        for (int i = 0; i < 4; ++i) {
            const int rowb = row0 + wr + i * 16 + quad * 4;
            #pragma unroll
            for (int r = 0; r < 4; ++r)
                C[(size_t)(rowb + r) * N + col] = acc[i][j][r] + bv;
        }
    }
}

// ---------------------------------------------------------------------------
// RoPE NeoX in-place on q (heads 0..35) and k (heads 36..39).
// ---------------------------------------------------------------------------
__global__ __launch_bounds__(64)
void rope_kernel(const int* __restrict__ positions, float* __restrict__ qkv)
{
    const int bh   = blockIdx.x;
    const int t    = bh / (NHEAD + NKVH);
    const int head = bh % (NHEAD + NKVH);
    const int d    = threadIdx.x;    // 0..63 = half dim
    float* base = qkv + (size_t)t * NQKV +
                  ((head < NHEAD) ? head * HEADDIM : KOFF + (head - NHEAD) * HEADDIM);
    const float inv_freq = __expf(-(float)d * (11.512925465f / 64.0f)); // 1e5^(-d/64)
    const float ang = (float)positions[t] * inv_freq;
    float s, c;
    sincosf(ang, &s, &c);
    const float x1 = base[d];
    const float x2 = base[d + 64];
    base[d]      = x1 * c - x2 * s;
    base[d + 64] = x2 * c + x1 * s;
}

// ---------------------------------------------------------------------------
// Windowed causal GQA flash attention, fp32.
// Block 256 thr per (head, 32-q tile). Thread (qi=tid>>3, e=tid&7) owns
// O/Q columns {4e+32c}. Scores: per-thread partial dots over its 16 d-cols
// for all 32 s, then 3-step __shfl_xor butterfly -> every thread holds the
// full score row; softmax entirely in registers (no Ss/Qs LDS, no serial
// phase). All LDS accesses are 8-distinct-address bank-disjoint or broadcast
// -> no padding needed. LDS = 32 KB -> 4 blocks/CU.
// ---------------------------------------------------------------------------
#define BQ 32
#define BS 32

__global__ __launch_bounds__(256, 4)
void attn_kernel(const float* __restrict__ qkv, float* __restrict__ out,
                 const int* __restrict__ windowp)
{
    __shared__ float Ks[BS][HEADDIM];
    __shared__ float Vs[BS][HEADDIM];

    const int h   = blockIdx.x;
    const int q0  = blockIdx.y * BQ;
    const int kvh = h / GQA_G;
    const int tid = threadIdx.x;
    const int qi  = tid >> 3;        // 0..31: q row (and staging row)
    const int e   = tid & 7;         // column-group owner
    const int window = *windowp;
    const int tg  = q0 + qi;
    const float scale = 0.088388347648318447f;  // 1/sqrt(128)

    float q[16], o[16];
    {
        const float* qp = qkv + (size_t)tg * NQKV + h * HEADDIM;
        #pragma unroll
        for (int c = 0; c < 4; ++c) {
            float4 v = *(const float4*)(qp + 4 * e + 32 * c);
            q[4 * c + 0] = v.x * scale; q[4 * c + 1] = v.y * scale;
            q[4 * c + 2] = v.z * scale; q[4 * c + 3] = v.w * scale;
        }
    }
    #pragma unroll
    for (int r = 0; r < 16; ++r) o[r] = 0.0f;
    float mrun = NEG_BIG, lrun = 0.0f;

    int s_lo = q0 - window + 1;
    if (s_lo < 0) s_lo = 0;
    s_lo &= ~(BS - 1);

    const int ep = (e + qi) & 7;     // permuted staging chunk (bank spread)
    const float* kbase = qkv + KOFF + kvh * HEADDIM;
    const float* vbase = qkv + VOFF + kvh * HEADDIM;

    for (int st = s_lo; st < q0 + BQ; st += BS) {
        __syncthreads();             // prev tile's Ks/Vs reads done
        {
            const float* kp = kbase + (size_t)(st + qi) * NQKV;
            const float* vp = vbase + (size_t)(st + qi) * NQKV;
            #pragma unroll
            for (int c = 0; c < 4; ++c) {
                const int col = 4 * ep + 32 * c;
                *(float4*)&Ks[qi][col] = *(const float4*)(kp + col);
                *(float4*)&Vs[qi][col] = *(const float4*)(vp + col);
            }
        }
        __syncthreads();

        // partial scores over own 16 d-columns, all 32 s
        float sc[BS];
        #pragma unroll
        for (int s = 0; s < BS; ++s) {
            float4 k0v = *(const float4*)&Ks[s][4 * e];
            float4 k1v = *(const float4*)&Ks[s][4 * e + 32];
            float4 k2v = *(const float4*)&Ks[s][4 * e + 64];
            float4 k3v = *(const float4*)&Ks[s][4 * e + 96];
            sc[s] = q[0] * k0v.x + q[1] * k0v.y + q[2]  * k0v.z + q[3]  * k0v.w
                  + q[4] * k1v.x + q[5] * k1v.y + q[6]  * k1v.z + q[7]  * k1v.w
                  + q[8] * k2v.x + q[9] * k2v.y + q[10] * k2v.z + q[11] * k2v.w
                  + q[12]* k3v.x + q[13]* k3v.y + q[14] * k3v.z + q[15] * k3v.w;
        }
        // butterfly over the 8 threads of the row -> all hold full scores
        #pragma unroll
        for (int m = 1; m <= 4; m <<= 1)
            #pragma unroll
            for (int s = 0; s < BS; ++s)
                sc[s] += __shfl_xor(sc[s], m);

        // mask + online softmax in registers (identical in all 8 lanes)
        float mx = mrun;
        #pragma unroll
        for (int s = 0; s < BS; ++s) {
            const int sg = st + s;
            const bool valid = (sg <= tg) && (sg > tg - window);
            sc[s] = valid ? sc[s] : NEG_BIG;
            mx = fmaxf(mx, sc[s]);
        }
        const float alpha = __expf(mrun - mx);   // exp(0)=1 while all-masked
        float sum = 0.0f;
        #pragma unroll
        for (int s = 0; s < BS; ++s) {
            const float p = (sc[s] > -5e29f) ? __expf(sc[s] - mx) : 0.0f;
            sc[s] = p;
            sum += p;
        }
        mrun = mx;
        lrun = lrun * alpha + sum;

        #pragma unroll
        for (int r = 0; r < 16; ++r) o[r] *= alpha;
        #pragma unroll
        for (int s = 0; s < BS; ++s) {
            const float p = sc[s];
            #pragma unroll
            for (int c = 0; c < 4; ++c) {
                float4 vv = *(const float4*)&Vs[s][4 * e + 32 * c];
                o[4 * c + 0] += p * vv.x; o[4 * c + 1] += p * vv.y;
                o[4 * c + 2] += p * vv.z; o[4 * c + 3] += p * vv.w;
            }
        }
    }

    const float inv = 1.0f / lrun;   // diagonal always valid => lrun > 0
    float* op = out + (size_t)tg * (NHEAD * HEADDIM) + h * HEADDIM;
    #pragma unroll
    for (int c = 0; c < 4; ++c) {
        float4 v = make_float4(o[4 * c] * inv, o[4 * c + 1] * inv,
                               o[4 * c + 2] * inv, o[4 * c + 3] * inv);
        *(float4*)&op[4 * e + 32 * c] = v;
    }
}

// ---------------------------------------------------------------------------
extern "C" void kernel_launch(void* const* d_in, const int* in_sizes, int n_in,
                              void* d_out, int out_size, void* d_ws, size_t ws_size,
                              hipStream_t stream)
{
    const int*   positions = (const int*)d_in[0];
    const float* hidden    = (const float*)d_in[1];
    const float* wqkv      = (const float*)d_in[2];
    const float* bqkv      = (const float*)d_in[3];
    const float* wo        = (const float*)d_in[4];
    const float* bo        = (const float*)d_in[5];
    const int*   windowp   = (const int*)d_in[6];
    float* outp = (float*)d_out;

    // ws: qkv [T,5632] fp32 (46.1 MB) | attn [T,4608] fp32 (37.7 MB)
    float* qkv  = (float*)d_ws;
    float* attn = qkv + (size_t)T_SEQ * NQKV;

    gemm_bf16_kernel<<<dim3(NQKV / 128, T_SEQ / 128), 256, 0, stream>>>(
        hidden, wqkv, bqkv, qkv, NQKV, HIDDEN);

    rope_kernel<<<T_SEQ * (NHEAD + NKVH), 64, 0, stream>>>(positions, qkv);

    attn_kernel<<<dim3(NHEAD, T_SEQ / BQ), 256, 0, stream>>>(qkv, attn, windowp);

    gemm_bf16_kernel<<<dim3(HIDDEN / 128, T_SEQ / 128), 256, 0, stream>>>(
        attn, wo, bo, outp, HIDDEN, HIDDEN);
}

// Round 3
// 2111.924 us; speedup vs baseline: 2.6988x; 2.6988x over previous
//
#include <hip/hip_runtime.h>
#include <hip/hip_bf16.h>
#include <math.h>

// Starcoder2 attention R3:
//  - GEMMs: bf16 MFMA (16x16x32), 128x128 tile, BK=32 (unchanged from R2,
//    ~800 TF measured).
//  - Attention: fp32 register softmax (unchanged algorithm) but WITHOUT the
//    __launch_bounds__ min-waves hint: R2's (256,4) capped VGPRs at 64 and
//    spilled sc[32]+o[16] to scratch -> 23.6 GB HBM traffic, 5.4 ms. Plain
//    (256) gives a 256-VGPR cap; live set ~110 fits, zero spills.
// T=2048, HID=4608, H=36, KV=4, D=128, window=1024.

#define T_SEQ   2048
#define HIDDEN  4608
#define NHEAD   36
#define NKVH    4
#define HEADDIM 128
#define GQA_G   9
#define NQKV    5632
#define KOFF    4608
#define VOFF    5120
#define NEG_BIG -1e30f

typedef short bf16x8 __attribute__((ext_vector_type(8)));
typedef float f32x4  __attribute__((ext_vector_type(4)));

// pack 8 fp32 -> 8 bf16 (RNE via v_cvt_pk_bf16_f32)
__device__ inline bf16x8 pack8(float4 u, float4 v) {
    union { bf16x8 v8; __hip_bfloat162 h[4]; } r;
    r.h[0] = __float22bfloat162_rn(make_float2(u.x, u.y));
    r.h[1] = __float22bfloat162_rn(make_float2(u.z, u.w));
    r.h[2] = __float22bfloat162_rn(make_float2(v.x, v.y));
    r.h[3] = __float22bfloat162_rn(make_float2(v.z, v.w));
    return r.v8;
}

// ---------------------------------------------------------------------------
// C[M,N] = A[M,K](fp32) @ B[N,K](fp32)^T + bias, bf16 MFMA, fp32 accumulate.
// 256 thr = 4 waves (2x2 of 64x64). Per wave: 4x4 grid of 16x16x32 MFMA.
// C/D layout (m89-verified): col = lane&15, row = (lane>>4)*4 + reg.
// ---------------------------------------------------------------------------
__global__ __launch_bounds__(256)
void gemm_bf16_kernel(const float* __restrict__ A, const float* __restrict__ B,
                      const float* __restrict__ bias, float* __restrict__ C,
                      int N, int K)
{
    __shared__ short As[128 * 32];   // row-major, row stride 32 bf16 (64 B)
    __shared__ short Bs[128 * 32];

    const int tid  = threadIdx.x;
    const int lane = tid & 63;
    const int wave = tid >> 6;
    const int row0 = blockIdx.y * 128;
    const int col0 = blockIdx.x * 128;
    const int wr   = (wave >> 1) * 64;
    const int wc   = (wave & 1) * 64;

    // staging: thread covers rows sr and sr+64, 8-float chunk sk
    const int sr = tid >> 2;          // 0..63
    const int sk = (tid & 3) * 8;     // element offset in K-tile

    const float* Ap  = A + (size_t)(row0 + sr) * K + sk;
    const float* Ap2 = Ap + (size_t)64 * K;
    const float* Bp  = B + (size_t)(col0 + sr) * K + sk;
    const float* Bp2 = Bp + (size_t)64 * K;

    f32x4 acc[4][4];
    #pragma unroll
    for (int i = 0; i < 4; ++i)
        #pragma unroll
        for (int j = 0; j < 4; ++j)
            #pragma unroll
            for (int r = 0; r < 4; ++r) acc[i][j][r] = 0.0f;

    // preload k0 = 0
    float4 a0 = *(const float4*)(Ap),  a1 = *(const float4*)(Ap + 4);
    float4 c0 = *(const float4*)(Ap2), c1 = *(const float4*)(Ap2 + 4);
    float4 b0 = *(const float4*)(Bp),  b1 = *(const float4*)(Bp + 4);
    float4 d0 = *(const float4*)(Bp2), d1 = *(const float4*)(Bp2 + 4);

    const int fr = lane & 15;          // row/col within 16-tile
    const int fk = (lane >> 4) * 8;    // k offset (elements)

    bf16x8* As_w  = (bf16x8*)&As[sr * 32 + sk];
    bf16x8* As_w2 = (bf16x8*)&As[(64 + sr) * 32 + sk];
    bf16x8* Bs_w  = (bf16x8*)&Bs[sr * 32 + sk];
    bf16x8* Bs_w2 = (bf16x8*)&Bs[(64 + sr) * 32 + sk];

    for (int k0 = 0; k0 < K; k0 += 32) {
        __syncthreads();                      // prev iter's ds_reads done
        *As_w  = pack8(a0, a1);
        *As_w2 = pack8(c0, c1);
        *Bs_w  = pack8(b0, b1);
        *Bs_w2 = pack8(d0, d1);
        __syncthreads();

        // prefetch next K-tile; overlaps the MFMA phase below
        if (k0 + 32 < K) {
            Ap += 32; Ap2 += 32; Bp += 32; Bp2 += 32;
            a0 = *(const float4*)(Ap);  a1 = *(const float4*)(Ap + 4);
            c0 = *(const float4*)(Ap2); c1 = *(const float4*)(Ap2 + 4);
            b0 = *(const float4*)(Bp);  b1 = *(const float4*)(Bp + 4);
            d0 = *(const float4*)(Bp2); d1 = *(const float4*)(Bp2 + 4);
        }

        bf16x8 af[4], bfr[4];
        #pragma unroll
        for (int i = 0; i < 4; ++i)
            af[i] = *(const bf16x8*)&As[(wr + i * 16 + fr) * 32 + fk];
        #pragma unroll
        for (int j = 0; j < 4; ++j)
            bfr[j] = *(const bf16x8*)&Bs[(wc + j * 16 + fr) * 32 + fk];

        #pragma unroll
        for (int i = 0; i < 4; ++i)
            #pragma unroll
            for (int j = 0; j < 4; ++j)
                acc[i][j] = __builtin_amdgcn_mfma_f32_16x16x32_bf16(
                    af[i], bfr[j], acc[i][j], 0, 0, 0);
    }

    const int quad = lane >> 4;
    #pragma unroll
    for (int j = 0; j < 4; ++j) {
        const int col = col0 + wc + j * 16 + fr;
        const float bv = bias[col];
        #pragma unroll
        for (int i = 0; i < 4; ++i) {
            const int rowb = row0 + wr + i * 16 + quad * 4;
            #pragma unroll
            for (int r = 0; r < 4; ++r)
                C[(size_t)(rowb + r) * N + col] = acc[i][j][r] + bv;
        }
    }
}

// ---------------------------------------------------------------------------
// RoPE NeoX in-place on q (heads 0..35) and k (heads 36..39).
// ---------------------------------------------------------------------------
__global__ __launch_bounds__(64)
void rope_kernel(const int* __restrict__ positions, float* __restrict__ qkv)
{
    const int bh   = blockIdx.x;
    const int t    = bh / (NHEAD + NKVH);
    const int head = bh % (NHEAD + NKVH);
    const int d    = threadIdx.x;    // 0..63 = half dim
    float* base = qkv + (size_t)t * NQKV +
                  ((head < NHEAD) ? head * HEADDIM : KOFF + (head - NHEAD) * HEADDIM);
    const float inv_freq = __expf(-(float)d * (11.512925465f / 64.0f)); // 1e5^(-d/64)
    const float ang = (float)positions[t] * inv_freq;
    float s, c;
    sincosf(ang, &s, &c);
    const float x1 = base[d];
    const float x2 = base[d + 64];
    base[d]      = x1 * c - x2 * s;
    base[d + 64] = x2 * c + x1 * s;
}

// ---------------------------------------------------------------------------
// Windowed causal GQA flash attention, fp32.
// Block 256 thr per (head, 32-q tile). Thread (qi=tid>>3, e=tid&7) owns
// O/Q columns {4e+32c}. Scores: per-thread partial dots over its 16 d-cols
// for all 32 s, then 3-step __shfl_xor butterfly -> every thread holds the
// full score row; softmax entirely in registers. All LDS accesses are
// 8-distinct-address bank-disjoint or broadcast (R2: conflicts == 0).
// NOTE: no min-waves launch_bounds hint — (256,4) in R2 capped VGPRs at 64,
// spilling sc[32]/o[16] to scratch (23.6 GB HBM traffic). Live set needs
// ~110 VGPRs; plain (256) lets it fit, VGPR-bound at ~4 waves/EU anyway.
// ---------------------------------------------------------------------------
#define BQ 32
#define BS 32

__global__ __launch_bounds__(256)
void attn_kernel(const float* __restrict__ qkv, float* __restrict__ out,
                 const int* __restrict__ windowp)
{
    __shared__ float Ks[BS][HEADDIM];
    __shared__ float Vs[BS][HEADDIM];

    const int h   = blockIdx.x;
    const int q0  = blockIdx.y * BQ;
    const int kvh = h / GQA_G;
    const int tid = threadIdx.x;
    const int qi  = tid >> 3;        // 0..31: q row (and staging row)
    const int e   = tid & 7;         // column-group owner
    const int window = *windowp;
    const int tg  = q0 + qi;
    const float scale = 0.088388347648318447f;  // 1/sqrt(128)

    float q[16], o[16];
    {
        const float* qp = qkv + (size_t)tg * NQKV + h * HEADDIM;
        #pragma unroll
        for (int c = 0; c < 4; ++c) {
            float4 v = *(const float4*)(qp + 4 * e + 32 * c);
            q[4 * c + 0] = v.x * scale; q[4 * c + 1] = v.y * scale;
            q[4 * c + 2] = v.z * scale; q[4 * c + 3] = v.w * scale;
        }
    }
    #pragma unroll
    for (int r = 0; r < 16; ++r) o[r] = 0.0f;
    float mrun = NEG_BIG, lrun = 0.0f;

    int s_lo = q0 - window + 1;
    if (s_lo < 0) s_lo = 0;
    s_lo &= ~(BS - 1);

    const int ep = (e + qi) & 7;     // permuted staging chunk (bank spread)
    const float* kbase = qkv + KOFF + kvh * HEADDIM;
    const float* vbase = qkv + VOFF + kvh * HEADDIM;

    for (int st = s_lo; st < q0 + BQ; st += BS) {
        __syncthreads();             // prev tile's Ks/Vs reads done
        {
            const float* kp = kbase + (size_t)(st + qi) * NQKV;
            const float* vp = vbase + (size_t)(st + qi) * NQKV;
            #pragma unroll
            for (int c = 0; c < 4; ++c) {
                const int col = 4 * ep + 32 * c;
                *(float4*)&Ks[qi][col] = *(const float4*)(kp + col);
                *(float4*)&Vs[qi][col] = *(const float4*)(vp + col);
            }
        }
        __syncthreads();

        // partial scores over own 16 d-columns, all 32 s
        float sc[BS];
        #pragma unroll
        for (int s = 0; s < BS; ++s) {
            float4 k0v = *(const float4*)&Ks[s][4 * e];
            float4 k1v = *(const float4*)&Ks[s][4 * e + 32];
            float4 k2v = *(const float4*)&Ks[s][4 * e + 64];
            float4 k3v = *(const float4*)&Ks[s][4 * e + 96];
            sc[s] = q[0] * k0v.x + q[1] * k0v.y + q[2]  * k0v.z + q[3]  * k0v.w
                  + q[4] * k1v.x + q[5] * k1v.y + q[6]  * k1v.z + q[7]  * k1v.w
                  + q[8] * k2v.x + q[9] * k2v.y + q[10] * k2v.z + q[11] * k2v.w
                  + q[12]* k3v.x + q[13]* k3v.y + q[14] * k3v.z + q[15] * k3v.w;
        }
        // butterfly over the 8 threads of the row -> all hold full scores
        #pragma unroll
        for (int m = 1; m <= 4; m <<= 1)
            #pragma unroll
            for (int s = 0; s < BS; ++s)
                sc[s] += __shfl_xor(sc[s], m);

        // mask + online softmax in registers (identical in all 8 lanes)
        float mx = mrun;
        #pragma unroll
        for (int s = 0; s < BS; ++s) {
            const int sg = st + s;
            const bool valid = (sg <= tg) && (sg > tg - window);
            sc[s] = valid ? sc[s] : NEG_BIG;
            mx = fmaxf(mx, sc[s]);
        }
        const float alpha = __expf(mrun - mx);   // exp(0)=1 while all-masked
        float sum = 0.0f;
        #pragma unroll
        for (int s = 0; s < BS; ++s) {
            const float p = (sc[s] > -5e29f) ? __expf(sc[s] - mx) : 0.0f;
            sc[s] = p;
            sum += p;
        }
        mrun = mx;
        lrun = lrun * alpha + sum;

        #pragma unroll
        for (int r = 0; r < 16; ++r) o[r] *= alpha;
        #pragma unroll
        for (int s = 0; s < BS; ++s) {
            const float p = sc[s];
            #pragma unroll
            for (int c = 0; c < 4; ++c) {
                float4 vv = *(const float4*)&Vs[s][4 * e + 32 * c];
                o[4 * c + 0] += p * vv.x; o[4 * c + 1] += p * vv.y;
                o[4 * c + 2] += p * vv.z; o[4 * c + 3] += p * vv.w;
            }
        }
    }

    const float inv = 1.0f / lrun;   // diagonal always valid => lrun > 0
    float* op = out + (size_t)tg * (NHEAD * HEADDIM) + h * HEADDIM;
    #pragma unroll
    for (int c = 0; c < 4; ++c) {
        float4 v = make_float4(o[4 * c] * inv, o[4 * c + 1] * inv,
                               o[4 * c + 2] * inv, o[4 * c + 3] * inv);
        *(float4*)&op[4 * e + 32 * c] = v;
    }
}

// ---------------------------------------------------------------------------
extern "C" void kernel_launch(void* const* d_in, const int* in_sizes, int n_in,
                              void* d_out, int out_size, void* d_ws, size_t ws_size,
                              hipStream_t stream)
{
    const int*   positions = (const int*)d_in[0];
    const float* hidden    = (const float*)d_in[1];
    const float* wqkv      = (const float*)d_in[2];
    const float* bqkv      = (const float*)d_in[3];
    const float* wo        = (const float*)d_in[4];
    const float* bo        = (const float*)d_in[5];
    const int*   windowp   = (const int*)d_in[6];
    float* outp = (float*)d_out;

    // ws: qkv [T,5632] fp32 (46.1 MB) | attn [T,4608] fp32 (37.7 MB)
    float* qkv  = (float*)d_ws;
    float* attn = qkv + (size_t)T_SEQ * NQKV;

    gemm_bf16_kernel<<<dim3(NQKV / 128, T_SEQ / 128), 256, 0, stream>>>(
        hidden, wqkv, bqkv, qkv, NQKV, HIDDEN);

    rope_kernel<<<T_SEQ * (NHEAD + NKVH), 64, 0, stream>>>(positions, qkv);

    attn_kernel<<<dim3(NHEAD, T_SEQ / BQ), 256, 0, stream>>>(qkv, attn, windowp);

    gemm_bf16_kernel<<<dim3(HIDDEN / 128, T_SEQ / 128), 256, 0, stream>>>(
        attn, wo, bo, outp, HIDDEN, HIDDEN);
}

// Round 4
// 815.603 us; speedup vs baseline: 6.9882x; 2.5894x over previous
//
#include <hip/hip_runtime.h>
#include <hip/hip_bf16.h>
#include <math.h>

// Starcoder2 attention R4:
//  - GEMMs: bf16 MFMA 128x128 tile (unchanged from R3).
//  - Attention: MFMA flash attention. BQ=64 (4 waves x 16 q-rows), BS=32.
//    QK^T: Q,K split hi/lo bf16 -> 3 MFMAs per 16x16 S tile (error ~1e-4).
//    Softmax on C-layout accs (row=quad*4+reg, col=lane&15), shfl_xor row
//    reduce. P -> per-wave LDS -> A-layout frag (no barrier: intra-wave).
//    PV: P(bf16) x Vt(bf16), V staged transposed. All LDS strides 16B-aligned.
// T=2048, HID=4608, H=36, KV=4, D=128, window=1024.

#define T_SEQ   2048
#define HIDDEN  4608
#define NHEAD   36
#define NKVH    4
#define HEADDIM 128
#define GQA_G   9
#define NQKV    5632
#define KOFF    4608
#define VOFF    5120
#define NEG_BIG -1e30f

typedef short bf16x8 __attribute__((ext_vector_type(8)));
typedef float f32x4  __attribute__((ext_vector_type(4)));

// pack 8 fp32 -> 8 bf16 (RNE)
__device__ inline bf16x8 pack8(float4 u, float4 v) {
    union { bf16x8 v8; __hip_bfloat162 h[4]; } r;
    r.h[0] = __float22bfloat162_rn(make_float2(u.x, u.y));
    r.h[1] = __float22bfloat162_rn(make_float2(u.z, u.w));
    r.h[2] = __float22bfloat162_rn(make_float2(v.x, v.y));
    r.h[3] = __float22bfloat162_rn(make_float2(v.z, v.w));
    return r.v8;
}

// ---------------------------------------------------------------------------
// GEMM: C[M,N] = A[M,K](fp32) @ B[N,K](fp32)^T + bias  (bf16 MFMA, fp32 acc)
// ---------------------------------------------------------------------------
__global__ __launch_bounds__(256)
void gemm_bf16_kernel(const float* __restrict__ A, const float* __restrict__ B,
                      const float* __restrict__ bias, float* __restrict__ C,
                      int N, int K)
{
    __shared__ short As[128 * 32];
    __shared__ short Bs[128 * 32];

    const int tid  = threadIdx.x;
    const int lane = tid & 63;
    const int wave = tid >> 6;
    const int row0 = blockIdx.y * 128;
    const int col0 = blockIdx.x * 128;
    const int wr   = (wave >> 1) * 64;
    const int wc   = (wave & 1) * 64;

    const int sr = tid >> 2;
    const int sk = (tid & 3) * 8;

    const float* Ap  = A + (size_t)(row0 + sr) * K + sk;
    const float* Ap2 = Ap + (size_t)64 * K;
    const float* Bp  = B + (size_t)(col0 + sr) * K + sk;
    const float* Bp2 = Bp + (size_t)64 * K;

    f32x4 acc[4][4];
    #pragma unroll
    for (int i = 0; i < 4; ++i)
        #pragma unroll
        for (int j = 0; j < 4; ++j)
            #pragma unroll
            for (int r = 0; r < 4; ++r) acc[i][j][r] = 0.0f;

    float4 a0 = *(const float4*)(Ap),  a1 = *(const float4*)(Ap + 4);
    float4 c0 = *(const float4*)(Ap2), c1 = *(const float4*)(Ap2 + 4);
    float4 b0 = *(const float4*)(Bp),  b1 = *(const float4*)(Bp + 4);
    float4 d0 = *(const float4*)(Bp2), d1 = *(const float4*)(Bp2 + 4);

    const int fr = lane & 15;
    const int fk = (lane >> 4) * 8;

    bf16x8* As_w  = (bf16x8*)&As[sr * 32 + sk];
    bf16x8* As_w2 = (bf16x8*)&As[(64 + sr) * 32 + sk];
    bf16x8* Bs_w  = (bf16x8*)&Bs[sr * 32 + sk];
    bf16x8* Bs_w2 = (bf16x8*)&Bs[(64 + sr) * 32 + sk];

    for (int k0 = 0; k0 < K; k0 += 32) {
        __syncthreads();
        *As_w  = pack8(a0, a1);
        *As_w2 = pack8(c0, c1);
        *Bs_w  = pack8(b0, b1);
        *Bs_w2 = pack8(d0, d1);
        __syncthreads();

        if (k0 + 32 < K) {
            Ap += 32; Ap2 += 32; Bp += 32; Bp2 += 32;
            a0 = *(const float4*)(Ap);  a1 = *(const float4*)(Ap + 4);
            c0 = *(const float4*)(Ap2); c1 = *(const float4*)(Ap2 + 4);
            b0 = *(const float4*)(Bp);  b1 = *(const float4*)(Bp + 4);
            d0 = *(const float4*)(Bp2); d1 = *(const float4*)(Bp2 + 4);
        }

        bf16x8 af[4], bfr[4];
        #pragma unroll
        for (int i = 0; i < 4; ++i)
            af[i] = *(const bf16x8*)&As[(wr + i * 16 + fr) * 32 + fk];
        #pragma unroll
        for (int j = 0; j < 4; ++j)
            bfr[j] = *(const bf16x8*)&Bs[(wc + j * 16 + fr) * 32 + fk];

        #pragma unroll
        for (int i = 0; i < 4; ++i)
            #pragma unroll
            for (int j = 0; j < 4; ++j)
                acc[i][j] = __builtin_amdgcn_mfma_f32_16x16x32_bf16(
                    af[i], bfr[j], acc[i][j], 0, 0, 0);
    }

    const int quad = lane >> 4;
    #pragma unroll
    for (int j = 0; j < 4; ++j) {
        const int col = col0 + wc + j * 16 + fr;
        const float bv = bias[col];
        #pragma unroll
        for (int i = 0; i < 4; ++i) {
            const int rowb = row0 + wr + i * 16 + quad * 4;
            #pragma unroll
            for (int r = 0; r < 4; ++r)
                C[(size_t)(rowb + r) * N + col] = acc[i][j][r] + bv;
        }
    }
}

// ---------------------------------------------------------------------------
// RoPE NeoX in-place on q (heads 0..35) and k (heads 36..39).
// ---------------------------------------------------------------------------
__global__ __launch_bounds__(64)
void rope_kernel(const int* __restrict__ positions, float* __restrict__ qkv)
{
    const int bh   = blockIdx.x;
    const int t    = bh / (NHEAD + NKVH);
    const int head = bh % (NHEAD + NKVH);
    const int d    = threadIdx.x;
    float* base = qkv + (size_t)t * NQKV +
                  ((head < NHEAD) ? head * HEADDIM : KOFF + (head - NHEAD) * HEADDIM);
    const float inv_freq = __expf(-(float)d * (11.512925465f / 64.0f)); // 1e5^(-d/64)
    const float ang = (float)positions[t] * inv_freq;
    float s, c;
    sincosf(ang, &s, &c);
    const float x1 = base[d];
    const float x2 = base[d + 64];
    base[d]      = x1 * c - x2 * s;
    base[d + 64] = x2 * c + x1 * s;
}

// ---------------------------------------------------------------------------
// MFMA flash attention (windowed causal GQA).
// Block: 256 thr = 4 waves; wave w owns q rows [q0+16w, q0+16w+16).
// Per 32-key tile: S(16x32) = 2 subtile MFMAs x 4 ksteps x 3(hi/lo);
// softmax on C-layout regs; P via per-wave LDS to A-layout; PV: 8 MFMAs.
// LDS strides: K rows 136 bf16 (272 B), Vt/P rows 40 bf16 (80 B) — all
// 16B-aligned for ds_*_b128, <=2-way bank aliasing.
// ---------------------------------------------------------------------------
#define BQ 64
#define BS 32
#define KSTR 136
#define VSTR 40
#define PSTR 40

__global__ __launch_bounds__(256)
void attn_kernel(const float* __restrict__ qkv, float* __restrict__ out,
                 const int* __restrict__ windowp)
{
    __shared__ short Kh[BS * KSTR];                 // 8704 B
    __shared__ short Kl[BS * KSTR];                 // 8704 B
    __shared__ short Vt[HEADDIM * VSTR];            // 10240 B
    __shared__ __hip_bfloat16 Ps[4][16 * PSTR];     // 5120 B

    const int h    = blockIdx.x;
    const int q0   = blockIdx.y * BQ;
    const int kvh  = h / GQA_G;
    const int tid  = threadIdx.x;
    const int lane = tid & 63;
    const int wave = tid >> 6;
    const int l15  = lane & 15;
    const int quad = lane >> 4;
    const int window = *windowp;
    const float scale = 0.088388347648318447f;  // 1/sqrt(128)

    // ---- Q A-fragments (hi/lo split), scale folded; A row m = l15
    bf16x8 qh[4], ql[4];
    {
        const float* qp = qkv + (size_t)(q0 + wave * 16 + l15) * NQKV
                        + h * HEADDIM + quad * 8;
        #pragma unroll
        for (int ks = 0; ks < 4; ++ks) {
            union { bf16x8 v; __hip_bfloat16 x[8]; } H, L;
            #pragma unroll
            for (int j = 0; j < 8; ++j) {
                const float v = qp[ks * 32 + j] * scale;
                const __hip_bfloat16 hb = __float2bfloat16(v);
                H.x[j] = hb;
                L.x[j] = __float2bfloat16(v - __bfloat162float(hb));
            }
            qh[ks] = H.v; ql[ks] = L.v;
        }
    }

    f32x4 o[8];
    #pragma unroll
    for (int c = 0; c < 8; ++c)
        #pragma unroll
        for (int r = 0; r < 4; ++r) o[c][r] = 0.0f;
    float mrun[4], lrun[4];
    #pragma unroll
    for (int r = 0; r < 4; ++r) { mrun[r] = NEG_BIG; lrun[r] = 0.0f; }

    // staging maps
    const int ksr = tid >> 3;            // K row 0..31
    const int ksc = (tid & 7) * 16;      // K col base
    const int vcl = tid & 15;            // V col lane
    const int vr  = (tid >> 4) * 2;      // V row pair (even)

    int s_lo = q0 - window + 1;
    if (s_lo < 0) s_lo = 0;
    s_lo &= ~(BS - 1);

    __hip_bfloat16* Psw = &Ps[wave][0];

    for (int st = s_lo; st < q0 + BQ; st += BS) {
        __syncthreads();   // prev tile's Kh/Kl/Vt reads done
        // ---- stage K hi/lo
        {
            const float* kp = qkv + (size_t)(st + ksr) * NQKV + KOFF
                            + kvh * HEADDIM + ksc;
            float kf[16];
            *(float4*)&kf[0]  = *(const float4*)(kp);
            *(float4*)&kf[4]  = *(const float4*)(kp + 4);
            *(float4*)&kf[8]  = *(const float4*)(kp + 8);
            *(float4*)&kf[12] = *(const float4*)(kp + 12);
            union { bf16x8 v; __hip_bfloat16 x[8]; } H0, H1, L0, L1;
            #pragma unroll
            for (int j = 0; j < 8; ++j) {
                const __hip_bfloat16 h0 = __float2bfloat16(kf[j]);
                const __hip_bfloat16 h1 = __float2bfloat16(kf[8 + j]);
                H0.x[j] = h0; H1.x[j] = h1;
                L0.x[j] = __float2bfloat16(kf[j]     - __bfloat162float(h0));
                L1.x[j] = __float2bfloat16(kf[8 + j] - __bfloat162float(h1));
            }
            *(bf16x8*)&Kh[ksr * KSTR + ksc]     = H0.v;
            *(bf16x8*)&Kh[ksr * KSTR + ksc + 8] = H1.v;
            *(bf16x8*)&Kl[ksr * KSTR + ksc]     = L0.v;
            *(bf16x8*)&Kl[ksr * KSTR + ksc + 8] = L1.v;
        }
        // ---- stage V transposed: Vt[d][s]
        {
            const float* vp = qkv + (size_t)(st + vr) * NQKV + VOFF
                            + kvh * HEADDIM;
            #pragma unroll
            for (int i = 0; i < 8; ++i) {
                const int d = vcl + 16 * i;
                const float v0 = vp[d];
                const float v1 = vp[NQKV + d];
                *(__hip_bfloat162*)&Vt[d * VSTR + vr] =
                    __float22bfloat162_rn(make_float2(v0, v1));
            }
        }
        __syncthreads();

        // ---- S = Q K^T  (two 16x16 subtiles over s)
        f32x4 acc0, acc1;
        #pragma unroll
        for (int r = 0; r < 4; ++r) { acc0[r] = 0.0f; acc1[r] = 0.0f; }
        #pragma unroll
        for (int ks = 0; ks < 4; ++ks) {
            const int ko = ks * 32 + quad * 8;
            const bf16x8 bh0 = *(const bf16x8*)&Kh[l15 * KSTR + ko];
            const bf16x8 bl0 = *(const bf16x8*)&Kl[l15 * KSTR + ko];
            const bf16x8 bh1 = *(const bf16x8*)&Kh[(16 + l15) * KSTR + ko];
            const bf16x8 bl1 = *(const bf16x8*)&Kl[(16 + l15) * KSTR + ko];
            acc0 = __builtin_amdgcn_mfma_f32_16x16x32_bf16(qh[ks], bh0, acc0, 0, 0, 0);
            acc1 = __builtin_amdgcn_mfma_f32_16x16x32_bf16(qh[ks], bh1, acc1, 0, 0, 0);
            acc0 = __builtin_amdgcn_mfma_f32_16x16x32_bf16(ql[ks], bh0, acc0, 0, 0, 0);
            acc1 = __builtin_amdgcn_mfma_f32_16x16x32_bf16(ql[ks], bh1, acc1, 0, 0, 0);
            acc0 = __builtin_amdgcn_mfma_f32_16x16x32_bf16(qh[ks], bl0, acc0, 0, 0, 0);
            acc1 = __builtin_amdgcn_mfma_f32_16x16x32_bf16(qh[ks], bl1, acc1, 0, 0, 0);
        }

        // ---- mask + online softmax on C-layout (row=quad*4+r, col=l15)
        const int qb  = q0 + wave * 16 + quad * 4;
        const int s0g = st + l15;
        const int s1g = st + 16 + l15;
        #pragma unroll
        for (int r = 0; r < 4; ++r) {
            const int q = qb + r;
            const bool v0 = (s0g <= q) && (s0g > q - window);
            const bool v1 = (s1g <= q) && (s1g > q - window);
            float a = v0 ? acc0[r] : NEG_BIG;
            float b = v1 ? acc1[r] : NEG_BIG;
            float mx = fmaxf(a, b);
            mx = fmaxf(mx, __shfl_xor(mx, 1));
            mx = fmaxf(mx, __shfl_xor(mx, 2));
            mx = fmaxf(mx, __shfl_xor(mx, 4));
            mx = fmaxf(mx, __shfl_xor(mx, 8));
            mx = fmaxf(mrun[r], mx);
            const float alpha = __expf(mrun[r] - mx);   // 1 while all-masked
            mrun[r] = mx;
            const float e0 = v0 ? __expf(acc0[r] - mx) : 0.0f;
            const float e1 = v1 ? __expf(acc1[r] - mx) : 0.0f;
            const __hip_bfloat162 pp = __float22bfloat162_rn(make_float2(e0, e1));
            Psw[(quad * 4 + r) * PSTR + l15]      = pp.x;
            Psw[(quad * 4 + r) * PSTR + 16 + l15] = pp.y;
            float sum = __bfloat162float(pp.x) + __bfloat162float(pp.y);
            sum += __shfl_xor(sum, 1);
            sum += __shfl_xor(sum, 2);
            sum += __shfl_xor(sum, 4);
            sum += __shfl_xor(sum, 8);
            lrun[r] = lrun[r] * alpha + sum;
            #pragma unroll
            for (int c = 0; c < 8; ++c) o[c][r] *= alpha;
        }

        // ---- PV: A = P (A-layout from LDS), B = Vt rows (n=d)
        const bf16x8 pa = *(const bf16x8*)&Psw[l15 * PSTR + quad * 8];
        #pragma unroll
        for (int c = 0; c < 8; ++c) {
            const bf16x8 vb = *(const bf16x8*)&Vt[(16 * c + l15) * VSTR + quad * 8];
            o[c] = __builtin_amdgcn_mfma_f32_16x16x32_bf16(pa, vb, o[c], 0, 0, 0);
        }
    }

    // ---- epilogue: normalize, write out[q][h*128 + d]
    #pragma unroll
    for (int r = 0; r < 4; ++r) {
        const float inv = 1.0f / lrun[r];   // diagonal always valid
        float* op = out + (size_t)(q0 + wave * 16 + quad * 4 + r) * (NHEAD * HEADDIM)
                  + h * HEADDIM + l15;
        #pragma unroll
        for (int c = 0; c < 8; ++c) op[16 * c] = o[c][r] * inv;
    }
}

// ---------------------------------------------------------------------------
extern "C" void kernel_launch(void* const* d_in, const int* in_sizes, int n_in,
                              void* d_out, int out_size, void* d_ws, size_t ws_size,
                              hipStream_t stream)
{
    const int*   positions = (const int*)d_in[0];
    const float* hidden    = (const float*)d_in[1];
    const float* wqkv      = (const float*)d_in[2];
    const float* bqkv      = (const float*)d_in[3];
    const float* wo        = (const float*)d_in[4];
    const float* bo        = (const float*)d_in[5];
    const int*   windowp   = (const int*)d_in[6];
    float* outp = (float*)d_out;

    // ws: qkv [T,5632] fp32 (46.1 MB) | attn [T,4608] fp32 (37.7 MB)
    float* qkv  = (float*)d_ws;
    float* attn = qkv + (size_t)T_SEQ * NQKV;

    gemm_bf16_kernel<<<dim3(NQKV / 128, T_SEQ / 128), 256, 0, stream>>>(
        hidden, wqkv, bqkv, qkv, NQKV, HIDDEN);

    rope_kernel<<<T_SEQ * (NHEAD + NKVH), 64, 0, stream>>>(positions, qkv);

    attn_kernel<<<dim3(NHEAD, T_SEQ / BQ), 256, 0, stream>>>(qkv, attn, windowp);

    gemm_bf16_kernel<<<dim3(HIDDEN / 128, T_SEQ / 128), 256, 0, stream>>>(
        attn, wo, bo, outp, HIDDEN, HIDDEN);
}